// Round 1
// baseline (1285.776 us; speedup 1.0000x reference)
//
#include <hip/hip_runtime.h>
#include <cstdint>
#include <cstddef>

// GCN_52012053955018 — round 1 (first real implementation)
//
// Pipeline (all f32):
//   prep:    W1T/VT transposes + zero acc1/acc2
//   dense:   xw1 = x@W1 ; right = 0.5*(gamma*relu(0.5*((xV)^2 - (x^2)(V^2))) + beta)
//   spmm1:   acc1[r] += val * xw1[c]        (atomic scatter, 8-wide)
//   mid:     h = 0.5*relu(acc1+b1) + right ; hw2 = h@W2   (8x16)
//   spmm2:   acc2[r] += val * hw2[c]        (atomic scatter, 16-wide)
//   softmax: out = log_softmax(acc2 + b2)
//
// ws layout (floats): [acc1 n*8][acc2 n*16][xw1 n*8][right n*8][hw2 n*16][W1T 4096][VT 4096]

#define NFEAT 512
#define NHID 8
#define NCLASS 16

__global__ __launch_bounds__(256) void prep_kernel(
    const float* __restrict__ W1, const float* __restrict__ V,
    float* __restrict__ W1T, float* __restrict__ VT,
    float4* __restrict__ zero_base, int zero_count4)
{
    int tid = blockIdx.x * 256 + threadIdx.x;
    if (tid < NFEAT * NHID) {
        int k = tid >> 3, j = tid & 7;
        W1T[j * NFEAT + k] = W1[tid];
        VT[j * NFEAT + k] = V[tid];
    }
    int stride = gridDim.x * 256;
    for (int i = tid; i < zero_count4; i += stride) {
        zero_base[i] = make_float4(0.f, 0.f, 0.f, 0.f);
    }
}

// thread = (node, j): j in [0,8). Full k-loop per thread, no reduction needed.
__global__ __launch_bounds__(256) void dense_kernel(
    const float* __restrict__ x,
    const float* __restrict__ W1T, const float* __restrict__ VT,
    const float* __restrict__ gamma, const float* __restrict__ beta,
    float* __restrict__ xw1, float* __restrict__ right, int n_nodes)
{
    int tid = blockIdx.x * 256 + threadIdx.x;
    int node = tid >> 3;
    if (node >= n_nodes) return;
    int j = tid & 7;

    const float4* __restrict__ xr  = (const float4*)(x + (size_t)node * NFEAT);
    const float4* __restrict__ w1r = (const float4*)(W1T + j * NFEAT);
    const float4* __restrict__ vr  = (const float4*)(VT + j * NFEAT);

    float a1 = 0.f;   // x @ W1
    float av = 0.f;   // x @ V
    float a2 = 0.f;   // (x*x) @ (V*V)
#pragma unroll 4
    for (int kk = 0; kk < NFEAT / 4; ++kk) {
        float4 xv = xr[kk];
        float4 wv = w1r[kk];
        float4 vv = vr[kk];
        a1 += xv.x * wv.x + xv.y * wv.y + xv.z * wv.z + xv.w * wv.w;
        av += xv.x * vv.x + xv.y * vv.y + xv.z * vv.z + xv.w * vv.w;
        a2 += (xv.x * xv.x) * (vv.x * vv.x)
            + (xv.y * xv.y) * (vv.y * vv.y)
            + (xv.z * xv.z) * (vv.z * vv.z)
            + (xv.w * xv.w) * (vv.w * vv.w);
    }
    xw1[tid] = a1;  // tid == node*8 + j
    float xr_relu = fmaxf(0.5f * (av * av - a2), 0.f);
    right[tid] = 0.5f * (gamma[j] * xr_relu + beta[j]);  // already includes h's 0.5
}

// 4 threads/edge, each handles 2 features via float2 gather.
__global__ __launch_bounds__(256) void spmm1_kernel(
    const int* __restrict__ rows, const int* __restrict__ cols,
    const float* __restrict__ vals, const float* __restrict__ xw1,
    float* __restrict__ acc1, int n_edges)
{
    int tid = blockIdx.x * 256 + threadIdx.x;
    int e = tid >> 2;
    if (e >= n_edges) return;
    int j = tid & 3;
    int r = rows[e], c = cols[e];
    float v = vals[e];
    float2 f = ((const float2*)xw1)[c * 4 + j];
    unsafeAtomicAdd(&acc1[r * NHID + 2 * j],     v * f.x);
    unsafeAtomicAdd(&acc1[r * NHID + 2 * j + 1], v * f.y);
}

// thread = (node, c): c in [0,16). hw2 = h @ W2.
__global__ __launch_bounds__(256) void mid_kernel(
    const float* __restrict__ acc1, const float* __restrict__ right,
    const float* __restrict__ b1, const float* __restrict__ W2,
    float* __restrict__ hw2, int n_nodes)
{
    int tid = blockIdx.x * 256 + threadIdx.x;
    int node = tid >> 4;
    if (node >= n_nodes) return;
    int c = tid & 15;
    const float* a  = acc1 + (size_t)node * NHID;
    const float* rr = right + (size_t)node * NHID;
    float s = 0.f;
#pragma unroll
    for (int j = 0; j < NHID; ++j) {
        float h = 0.5f * fmaxf(a[j] + b1[j], 0.f) + rr[j];
        s += h * W2[j * NCLASS + c];
    }
    hw2[tid] = s;  // tid == node*16 + c
}

// 8 threads/edge, each handles 2 classes via float2 gather.
__global__ __launch_bounds__(256) void spmm2_kernel(
    const int* __restrict__ rows, const int* __restrict__ cols,
    const float* __restrict__ vals, const float* __restrict__ hw2,
    float* __restrict__ acc2, int n_edges)
{
    int tid = blockIdx.x * 256 + threadIdx.x;
    int e = tid >> 3;
    if (e >= n_edges) return;
    int j = tid & 7;
    int r = rows[e], c = cols[e];
    float v = vals[e];
    float2 f = ((const float2*)hw2)[c * 8 + j];
    unsafeAtomicAdd(&acc2[r * NCLASS + 2 * j],     v * f.x);
    unsafeAtomicAdd(&acc2[r * NCLASS + 2 * j + 1], v * f.y);
}

__global__ __launch_bounds__(256) void softmax_kernel(
    const float* __restrict__ acc2, const float* __restrict__ b2,
    float* __restrict__ out, int n_nodes)
{
    int node = blockIdx.x * 256 + threadIdx.x;
    if (node >= n_nodes) return;
    const float4* zr = (const float4*)(acc2 + (size_t)node * NCLASS);
    const float4* bb = (const float4*)b2;
    float z[NCLASS];
#pragma unroll
    for (int q = 0; q < 4; ++q) {
        float4 t = zr[q];
        float4 b = bb[q];
        z[4 * q + 0] = t.x + b.x;
        z[4 * q + 1] = t.y + b.y;
        z[4 * q + 2] = t.z + b.z;
        z[4 * q + 3] = t.w + b.w;
    }
    float m = z[0];
#pragma unroll
    for (int i = 1; i < NCLASS; ++i) m = fmaxf(m, z[i]);
    float s = 0.f;
#pragma unroll
    for (int i = 0; i < NCLASS; ++i) s += expf(z[i] - m);
    float l = m + logf(s);
    float4* o = (float4*)(out + (size_t)node * NCLASS);
#pragma unroll
    for (int q = 0; q < 4; ++q) {
        float4 t;
        t.x = z[4 * q + 0] - l;
        t.y = z[4 * q + 1] - l;
        t.z = z[4 * q + 2] - l;
        t.w = z[4 * q + 3] - l;
        o[q] = t;
    }
}

extern "C" void kernel_launch(void* const* d_in, const int* in_sizes, int n_in,
                              void* d_out, int out_size, void* d_ws, size_t ws_size,
                              hipStream_t stream)
{
    const float* x     = (const float*)d_in[0];
    const int*   rows  = (const int*)  d_in[1];
    const int*   cols  = (const int*)  d_in[2];
    const float* vals  = (const float*)d_in[3];
    const float* W1    = (const float*)d_in[4];
    const float* b1    = (const float*)d_in[5];
    const float* W2    = (const float*)d_in[6];
    const float* b2    = (const float*)d_in[7];
    const float* V     = (const float*)d_in[8];
    const float* gamma = (const float*)d_in[9];
    const float* beta  = (const float*)d_in[10];

    const int n = in_sizes[0] / NFEAT;   // 100000
    const int e = in_sizes[1];           // 3200000

    float* ws    = (float*)d_ws;
    float* acc1  = ws;                               // n*8
    float* acc2  = ws + (size_t)n * 8;               // n*16
    float* xw1   = ws + (size_t)n * 24;              // n*8
    float* right = ws + (size_t)n * 32;              // n*8
    float* hw2   = ws + (size_t)n * 40;              // n*16
    float* W1T   = ws + (size_t)n * 56;              // 4096
    float* VT    = W1T + NFEAT * NHID;               // 4096

    // prep: transpose weights + zero acc1/acc2 (contiguous n*24 floats at ws start)
    int zero4 = (n * 24) / 4;
    int prep_blocks = (zero4 + 255) / 256;
    prep_kernel<<<prep_blocks, 256, 0, stream>>>(W1, V, W1T, VT, (float4*)ws, zero4);

    dense_kernel<<<(n * 8 + 255) / 256, 256, 0, stream>>>(x, W1T, VT, gamma, beta, xw1, right, n);

    spmm1_kernel<<<(e * 4 + 255) / 256, 256, 0, stream>>>(rows, cols, vals, xw1, acc1, e);

    mid_kernel<<<(n * 16 + 255) / 256, 256, 0, stream>>>(acc1, right, b1, W2, hw2, n);

    spmm2_kernel<<<(e * 8 + 255) / 256, 256, 0, stream>>>(rows, cols, vals, hw2, acc2, e);

    softmax_kernel<<<(n + 255) / 256, 256, 0, stream>>>(acc2, b2, (float*)d_out, n);
}